// Round 13
// baseline (417.967 us; speedup 1.0000x reference)
//
#include <hip/hip_runtime.h>
#include <hip/hip_bf16.h>

typedef __hip_bfloat16 bf16;
typedef unsigned int uint;
typedef unsigned short ushort;
typedef __attribute__((ext_vector_type(8))) short short8;  // 8 x bf16 (4 VGPRs)
typedef __attribute__((ext_vector_type(4))) float floatx4;

#define N_NODES 100000
#define N_PAD   100096   // multiple of 128 for the MFMA row tiling
#define E_EDGES 800000
#define NBLK    98       // ceil(N_NODES / 1024)
#define EBLK    3125     // E_EDGES / 256 (exact)
#define RBLK    782      // rank_k blocks: 782*256 = 200192 threads, 4 edges each

static __device__ __forceinline__ uint packbf(float a, float b) {
  bf16 x = __float2bfloat16(a), y = __float2bfloat16(b);
  ushort ux = *reinterpret_cast<ushort*>(&x);
  ushort uy = *reinterpret_cast<ushort*>(&y);
  return (uint)ux | ((uint)uy << 16);
}
static __device__ __forceinline__ float lo16(uint u) { return __uint_as_float(u << 16); }
static __device__ __forceinline__ float hi16(uint u) { return __uint_as_float(u & 0xffff0000u); }

// sum over each DPP row (16 lanes) via cyclic rotations 8,4,2,1 — every lane
// ends with the full 16-lane sum. Pure VALU (v_add dpp), no LDS pipe.
static __device__ __forceinline__ float rsum16(float p) {
  p += __int_as_float(__builtin_amdgcn_update_dpp(
      0, __float_as_int(p), 0x128, 0xF, 0xF, false));  // row_ror:8
  p += __int_as_float(__builtin_amdgcn_update_dpp(
      0, __float_as_int(p), 0x124, 0xF, 0xF, false));  // row_ror:4
  p += __int_as_float(__builtin_amdgcn_update_dpp(
      0, __float_as_int(p), 0x122, 0xF, 0xF, false));  // row_ror:2
  p += __int_as_float(__builtin_amdgcn_update_dpp(
      0, __float_as_int(p), 0x121, 0xF, 0xF, false));  // row_ror:1
  return p;
}

// ---------------- CSR build: rank-based (r10-proven) -------------------------
// Rank pass: returning atomics only. dst stream is single-use -> nt load so it
// does not evict the fi atomic window from L2.
__global__ __launch_bounds__(256) void rank_k(
    const int* __restrict__ dst0, const int* __restrict__ dst1,
    int* fi0, int* fi1, int* __restrict__ rk0, int* __restrict__ rk1) {
  int base = blockIdx.x * 256 + threadIdx.x;   // 0 .. 200191
  int rel = blockIdx.y;
  const int* dst = rel ? dst1 : dst0;
  int* fi = rel ? fi1 : fi0;
  int* rk = rel ? rk1 : rk0;
#pragma unroll
  for (int k = 0; k < 4; ++k) {
    int i = base + k * (RBLK * 256);
    if (i < E_EDGES) {
      int d = __builtin_nontemporal_load(dst + i);
      rk[i] = atomicAdd(&fi[d], 1);
    }
  }
}

// Scatter with NO atomics: pos = rp[dst] + rank. Single-use streams (dst, src,
// rk) use nt loads so the partially-dirty csd scatter lines can REST in L2
// until all ~8 writes per line arrive (kills the 8x writeback amplification).
// rp is reused (random re-gather) -> normal cached load. csd store cached.
__global__ __launch_bounds__(256) void scat_rank_k(
    const int* __restrict__ src0, const int* __restrict__ dst0,
    const int* __restrict__ src1, const int* __restrict__ dst1,
    const int* __restrict__ rk0, const int* __restrict__ rk1,
    const int* __restrict__ rp0, const int* __restrict__ rp1,
    int2* __restrict__ csd0, int2* __restrict__ csd1) {
  int i = blockIdx.x * 256 + threadIdx.x;
  int rel = blockIdx.y;
  const int* src = rel ? src1 : src0;
  const int* dst = rel ? dst1 : dst0;
  const int* rk = rel ? rk1 : rk0;
  const int* rp = rel ? rp1 : rp0;
  int2* csd = rel ? csd1 : csd0;
  int d = __builtin_nontemporal_load(dst + i);
  int s = __builtin_nontemporal_load(src + i);
  int r = __builtin_nontemporal_load(rk + i);
  int pos = rp[d] + r;
  csd[pos] = make_int2(s, d);
}

// shfl-based scan: 2 barriers instead of 20.
__global__ void scan_blk_k(const int* __restrict__ deg0, const int* __restrict__ deg1,
                           int* rp0, int* rp1, int* bsum) {
  __shared__ int ws[16];
  int r = blockIdx.y;
  const int* deg = r ? deg1 : deg0;
  int* rp = r ? rp1 : rp0;
  int i = blockIdx.x * 1024 + threadIdx.x;
  int v = (i < N_NODES) ? deg[i] : 0;
  int lane = threadIdx.x & 63, wid = threadIdx.x >> 6;
  int s = v;
#pragma unroll
  for (int off = 1; off < 64; off <<= 1) {
    int t = __shfl_up(s, off);
    if (lane >= off) s += t;
  }
  if (lane == 63) ws[wid] = s;
  __syncthreads();
  if (wid == 0) {
    int wv = (lane < 16) ? ws[lane] : 0;
#pragma unroll
    for (int off = 1; off < 16; off <<= 1) {
      int t = __shfl_up(wv, off);
      if (lane >= off) wv += t;
    }
    if (lane < 16) ws[lane] = wv;
  }
  __syncthreads();
  int base = wid ? ws[wid - 1] : 0;
  int incl = base + s;
  if (i < N_NODES) rp[i] = incl - v;              // exclusive prefix
  if (threadIdx.x == 1023) bsum[r * NBLK + blockIdx.x] = incl;  // block total
}

// scan_top folded in: each block computes its 98-element block-prefix inline
// (L2-hit loads + one 64-lane reduce). rp[N] = E_EDGES is a known constant.
__global__ void scan_add_k(const int* __restrict__ bsum,
                           int* rp0, int* rp1, int* fi0, int* fi1) {
  __shared__ int sbase;
  int r = blockIdx.y;
  int b = blockIdx.x;
  if (threadIdx.x < 64) {
    int j = threadIdx.x;
    int v = (j < b) ? bsum[r * NBLK + j] : 0;
    int j2 = j + 64;
    if (j2 < b) v += bsum[r * NBLK + j2];
#pragma unroll
    for (int off = 32; off >= 1; off >>= 1) v += __shfl_xor(v, off);
    if (j == 0) sbase = v;
  }
  __syncthreads();
  if (b == 0 && threadIdx.x == 0) (r ? rp1 : rp0)[N_NODES] = E_EDGES;
  int i = b * 1024 + threadIdx.x;
  if (i >= N_NODES) return;
  int* rp = r ? rp1 : rp0;
  int* fi = r ? fi1 : fi0;
  int val = rp[i] + sbase;
  rp[i] = val;
  fi[i] = val;
}

// ---------------- layer-2 weight prep + layer-1 tables ----------------------
__global__ void wprep_k(const float* __restrict__ Wl, const float* __restrict__ Wr,
                        short* __restrict__ WT,
                        const float* __restrict__ l1Wl, const float* __restrict__ l1bl,
                        const float* __restrict__ l1Wr, const float* __restrict__ l1br,
                        const float* __restrict__ l1att, float* __restrict__ L1C,
                        float* __restrict__ SCG) {
  if (blockIdx.x == 128) {
    __shared__ float lps[20][8];
    int t = threadIdx.x;
    {  // SCG fill: 2 rel x 128 channels, 6 values each
      int rel = t >> 7, c = t & 127;
      int ch = c >> 2, o = c & 3;
      float* g = SCG + rel * 768 + ch * 24;
      g[0 + o]  = l1bl[rel * 128 + c] + l1br[rel * 128 + c];
      g[4 + o]  = l1Wr[rel * 256 + c];
      g[8 + o]  = l1Wr[rel * 256 + 128 + c];
      g[12 + o] = l1Wl[rel * 256 + c];
      g[16 + o] = l1Wl[rel * 256 + 128 + c];
      g[20 + o] = l1att[rel * 128 + c];
    }
    // L1C: 20 values x 64 terms, parallel over 160 threads (8 terms each)
    if (t < 160) {
      int v5 = t >> 3, kk = t & 7;
      int rel = v5 / 10, rem = v5 % 10, h = rem / 5, vv = rem % 5;
      const float* a = l1att + rel * 128 + h * 64;
      float sum = 0.f;
      for (int c = kk * 8; c < kk * 8 + 8; ++c) {
        int cc = h * 64 + c;
        float val;
        if (vv == 0)      val = l1bl[rel * 128 + cc] + l1br[rel * 128 + cc];
        else if (vv == 1) val = l1Wr[rel * 256 + cc];
        else if (vv == 2) val = l1Wr[rel * 256 + 128 + cc];
        else if (vv == 3) val = l1Wl[rel * 256 + cc];
        else              val = l1Wl[rel * 256 + 128 + cc];
        sum += a[c] * val;
      }
      lps[v5][kk] = sum;
    }
    __syncthreads();
    if (t < 20) {
      float s = 0.f;
#pragma unroll
      for (int j = 0; j < 8; ++j) s += lps[t][j];
      L1C[t] = s;
    }
    return;
  }
  int id2 = blockIdx.x * 256 + threadIdx.x;
  int rel = id2 >> 14;
  int id = id2 & 16383;
  int c = id >> 6, k = id & 63;
  const float* W = (c < 128) ? (Wl + rel * 8192) : (Wr + rel * 8192);
  int cc = c & 127;
  bf16 b = __float2bfloat16(W[k * 128 + cc]);
  WT[rel * 16384 + c * 64 + k] = *reinterpret_cast<short*>(&b);
}

// ---------------- layer-1 scoring: EDGE-parallel, one lane = one edge --------
__global__ __launch_bounds__(256) void l1score_k(
    const int2* __restrict__ csd0, const int2* __restrict__ csd1,
    const float* __restrict__ x,
    const float* __restrict__ scg, const float* __restrict__ l1c,
    float4* __restrict__ EX4) {
  int rel = blockIdx.y;
  const int2* csd = rel ? csd1 : csd0;
  const float* sC = scg + rel * 768;
  const float* C = l1c + rel * 10;
  float q00 = C[0], qv00 = C[1], qv10 = C[2], qw00 = C[3], qw10 = C[4];
  float q01 = C[5], qv01 = C[6], qv11 = C[7], qw01 = C[8], qw11 = C[9];
  int i = blockIdx.x * 256 + threadIdx.x;  // grid is exact: 3125*256 == E_EDGES
  long long raw = __builtin_nontemporal_load((const long long*)csd + i);
  int s = (int)(raw & 0xffffffffll);
  int d = (int)(raw >> 32);
  float2 xs = *(const float2*)(x + 2 * s);
  float2 xd = *(const float2*)(x + 2 * d);
  float t0a = 0.f, t0b = 0.f, t1a = 0.f, t1b = 0.f;
#pragma unroll
  for (int ch = 0; ch < 32; ++ch) {
    const float4* cp = (const float4*)(sC + ch * 24);  // uniform address
    float4 bb = cp[0], v0 = cp[1], v1 = cp[2], w0 = cp[3], w1 = cp[4], aa = cp[5];
    float e0 = bb.x + xd.x * v0.x + xd.y * v1.x + xs.x * w0.x + xs.y * w1.x;
    float e1 = bb.y + xd.x * v0.y + xd.y * v1.y + xs.x * w0.y + xs.y * w1.y;
    float e2 = bb.z + xd.x * v0.z + xd.y * v1.z + xs.x * w0.z + xs.y * w1.z;
    float e3 = bb.w + xd.x * v0.w + xd.y * v1.w + xs.x * w0.w + xs.y * w1.w;
    if (ch < 16) {
      t0a = fmaf(aa.x, fabsf(e0), t0a); t0b = fmaf(aa.y, fabsf(e1), t0b);
      t0a = fmaf(aa.z, fabsf(e2), t0a); t0b = fmaf(aa.w, fabsf(e3), t0b);
    } else {
      t1a = fmaf(aa.x, fabsf(e0), t1a); t1b = fmaf(aa.y, fabsf(e1), t1b);
      t1a = fmaf(aa.z, fabsf(e2), t1a); t1b = fmaf(aa.w, fabsf(e3), t1b);
    }
  }
  float T0 = t0a + t0b, T1 = t1a + t1b;
  float lin0 = q00 + xd.x * qv00 + xd.y * qv10 + xs.x * qw00 + xs.y * qw10;
  float lin1 = q01 + xd.x * qv01 + xd.y * qv11 + xs.x * qw01 + xs.y * qw11;
  float p0 = fmaf(0.4f, T0, 0.6f * lin0);
  float p1 = fmaf(0.4f, T1, 0.6f * lin1);
  EX4[(size_t)rel * E_EDGES + i] = make_float4(__expf(p0), __expf(p1), xs.x, xs.y);
}

// ------- layer-1 agg + finish FUSED: LDS handoff, no NA global round-trip ----
__global__ __launch_bounds__(256) void l1aggfin_k(
    const int* __restrict__ rp0, const int* __restrict__ rp1,
    const float4* __restrict__ EX4,
    const float* __restrict__ Wl, const float* __restrict__ bl,
    const float* __restrict__ bias, uint2* __restrict__ HB2) {
  __shared__ __align__(16) float sNA[64][12];
  int t = threadIdx.x;
  int g = blockIdx.x * 64 + (t >> 2);   // dst for phase 1
  int k = t & 3;
  float p0 = 0.f, p1 = 0.f, p2 = 0.f, p3 = 0.f, p4 = 0.f, p5 = 0.f;
  float p6 = 0.f, p7 = 0.f, p8 = 0.f, p9 = 0.f, p10 = 0.f, p11 = 0.f;
  if (g < N_NODES) {
    {
      int beg = rp0[g], end = rp0[g + 1];
      for (int j = beg + k; j < end; j += 4) {
        float4 e = EX4[j];
        p0 += e.x; p1 = fmaf(e.x, e.z, p1); p2 = fmaf(e.x, e.w, p2);
        p3 += e.y; p4 = fmaf(e.y, e.z, p4); p5 = fmaf(e.y, e.w, p5);
      }
    }
    {
      const float4* E1 = EX4 + E_EDGES;
      int beg = rp1[g], end = rp1[g + 1];
      for (int j = beg + k; j < end; j += 4) {
        float4 e = E1[j];
        p6 += e.x; p7 = fmaf(e.x, e.z, p7); p8 = fmaf(e.x, e.w, p8);
        p9 += e.y; p10 = fmaf(e.y, e.z, p10); p11 = fmaf(e.y, e.w, p11);
      }
    }
  }
#define RED4(v) v += __shfl_xor(v, 1); v += __shfl_xor(v, 2);
  RED4(p0) RED4(p1) RED4(p2) RED4(p3) RED4(p4) RED4(p5)
  RED4(p6) RED4(p7) RED4(p8) RED4(p9) RED4(p10) RED4(p11)
#undef RED4
  {
    int dl = t >> 2;
    if (k == 0)      *(float4*)(&sNA[dl][0]) = make_float4(p0, p1, p2, p3);
    else if (k == 1) *(float4*)(&sNA[dl][4]) = make_float4(p4, p5, p6, p7);
    else if (k == 2) *(float4*)(&sNA[dl][8]) = make_float4(p8, p9, p10, p11);
  }
  __syncthreads();
#pragma unroll
  for (int rep = 0; rep < 4; ++rep) {
    int idx = rep * 256 + t;            // 0..1023
    int dl = idx >> 4, l = idx & 15;
    int d = blockIdx.x * 64 + dl;
    if (d >= N_NODES) continue;
    int c0 = 4 * l;
    const float* na = sNA[dl];
    float out0 = 0.f, out1 = 0.f, out2 = 0.f, out3 = 0.f;
#pragma unroll
    for (int r = 0; r < 2; ++r) {
      float a0c = 0.f, a1c = 0.f, a2c = 0.f, a3c = 0.f;
#pragma unroll
      for (int h = 0; h < 2; ++h) {
        float den = na[r * 6 + h * 3 + 0];
        float A0  = na[r * 6 + h * 3 + 1];
        float A1  = na[r * 6 + h * 3 + 2];
        float inv = 1.f / (den + 1e-16f);
        float a0 = A0 * inv, a1 = A1 * inv, S = den * inv;  // S: 1 normally, 0 empty
        float4 W0 = *(const float4*)(Wl + r * 256 + h * 64 + c0);
        float4 W1 = *(const float4*)(Wl + r * 256 + 128 + h * 64 + c0);
        float4 B  = *(const float4*)(bl + r * 128 + h * 64 + c0);
        a0c += a0 * W0.x + a1 * W1.x + S * B.x;
        a1c += a0 * W0.y + a1 * W1.y + S * B.y;
        a2c += a0 * W0.z + a1 * W1.z + S * B.z;
        a3c += a0 * W0.w + a1 * W1.w + S * B.w;
      }
      float4 bi = *(const float4*)(bias + r * 64 + c0);
      out0 += 0.5f * a0c + bi.x;
      out1 += 0.5f * a1c + bi.y;
      out2 += 0.5f * a2c + bi.z;
      out3 += 0.5f * a3c + bi.w;
    }
    out0 = fmaxf(0.5f * out0, 0.f); out1 = fmaxf(0.5f * out1, 0.f);
    out2 = fmaxf(0.5f * out2, 0.f); out3 = fmaxf(0.5f * out3, 0.f);
    HB2[(size_t)d * 16 + l] = make_uint2(packbf(out0, out1), packbf(out2, out3));
  }
}

// ---------------- layer-2 transform: swapped operands -> packed row stores ---
__global__ __launch_bounds__(256) void mfma_t_k(const bf16* __restrict__ HB,
                                                const short* __restrict__ WTb,
                                                const float* __restrict__ blb,
                                                const float* __restrict__ brb,
                                                bf16* __restrict__ XL0,
                                                bf16* __restrict__ XR0,
                                                bf16* __restrict__ XL1,
                                                bf16* __restrict__ XR1) {
  __shared__ short sW[256 * 72];
  int rel = blockIdx.z;
  const short* WT = WTb + rel * 16384;
  const float* bl = blb + rel * 128;
  const float* br = brb + rel * 128;
  bf16* XLp = rel ? XL1 : XL0;
  bf16* XRp = rel ? XR1 : XR0;
  int t = threadIdx.x;
#pragma unroll
  for (int i = 0; i < 8; ++i) {
    int chunk = t + i * 256;
    int c = chunk >> 3, off = (chunk & 7) * 8;
    *(short8*)(&sW[c * 72 + off]) = *(const short8*)(WT + chunk * 8);
  }
  __syncthreads();
  int wave = t >> 6, lane = t & 63;
  int q = lane >> 4, m = lane & 15;
  int rowbase = blockIdx.x * 128 + wave * 32;
  short8 afr[2][2];
#pragma unroll
  for (int rt = 0; rt < 2; ++rt)
#pragma unroll
    for (int kh = 0; kh < 2; ++kh) {
      size_t row = (size_t)(rowbase + rt * 16 + m);
      afr[rt][kh] = *(const short8*)((const short*)HB + row * 64 + kh * 32 + q * 8);
    }
  for (int ct = 0; ct < 16; ++ct) {
    int col = ct * 16 + m;
    short8 b0 = *(const short8*)(&sW[col * 72 + q * 8]);
    short8 b1 = *(const short8*)(&sW[col * 72 + 32 + q * 8]);
    int c0 = ct * 16 + q * 4;
    int c128 = c0 & 127;
    const float* bp = (ct < 8) ? bl : br;
    bf16* X = (ct < 8) ? XLp : XRp;
    float4 bv = *(const float4*)(bp + c128);
#pragma unroll
    for (int rt = 0; rt < 2; ++rt) {
      floatx4 acc = {0.f, 0.f, 0.f, 0.f};
      acc = __builtin_amdgcn_mfma_f32_16x16x32_bf16(b0, afr[rt][0], acc, 0, 0, 0);
      acc = __builtin_amdgcn_mfma_f32_16x16x32_bf16(b1, afr[rt][1], acc, 0, 0, 0);
      int node = rowbase + rt * 16 + m;
      if (node < N_NODES) {
        uint u0 = packbf(acc[0] + bv.x, acc[1] + bv.y);
        uint u1 = packbf(acc[2] + bv.z, acc[3] + bv.w);
        *(uint2*)((ushort*)X + (size_t)node * 128 + c128) = make_uint2(u0, u1);
      }
    }
  }
}

// ------- layer-2 agg: fused relations, 32 lanes/edge, quad-unrolled MLP=4 ----
struct EdgeAcc { float a0, a1, a2, a3, den; };

// abs-split score: p = 0.6*(sx + sxr) + 0.4*sum att|e|; the 0.6*sxr head-total
// (q06) is precomputed per wave. fabsf folds into the VOP3 input modifier.
static __device__ __forceinline__ void edge_step(
    uint2 u, float xr0, float xr1, float xr2, float xr3,
    float at0, float at1, float at2, float at3, float q06, EdgeAcc& A) {
  float x0 = lo16(u.x), x1 = hi16(u.x), x2 = lo16(u.y), x3 = hi16(u.y);
  float e0 = x0 + xr0, e1 = x1 + xr1, e2 = x2 + xr2, e3 = x3 + xr3;
  float sa = at0 * fabsf(e0);
  sa = fmaf(at1, fabsf(e1), sa);
  sa = fmaf(at2, fabsf(e2), sa);
  sa = fmaf(at3, fabsf(e3), sa);
  float sx = at0 * x0;
  sx = fmaf(at1, x1, sx);
  sx = fmaf(at2, x2, sx);
  sx = fmaf(at3, x3, sx);
  float p = fmaf(0.6f, sx, 0.4f * sa);
  p = rsum16(p);                // 16-lane head-group total, pure VALU DPP
  float ex = __expf(p + q06);
  A.den += ex;
  A.a0 = fmaf(ex, x0, A.a0);
  A.a1 = fmaf(ex, x1, A.a1);
  A.a2 = fmaf(ex, x2, A.a2);
  A.a3 = fmaf(ex, x3, A.a3);
}

__global__ __launch_bounds__(256) void aggf_k(
    const int* __restrict__ rp0, const int2* __restrict__ csd0,
    const int* __restrict__ rp1, const int2* __restrict__ csd1,
    const bf16* __restrict__ XL0, const bf16* __restrict__ XR0,
    const bf16* __restrict__ XL1, const bf16* __restrict__ XR1,
    const float* __restrict__ att,    // [256]: rel0 at +0, rel1 at +128
    const float* __restrict__ bias,   // [128]: rel0 at +0, rel1 at +64
    float* __restrict__ outf) {
  int d = (blockIdx.x * 256 + threadIdx.x) >> 6;
  int lane = threadIdx.x & 63;
  if (d >= N_NODES) return;
  int half = lane >> 5;
  int l = lane & 31;
  int beg0 = rp0[d], end0 = rp0[d + 1];
  int beg1 = rp1[d], end1 = rp1[d + 1];
  const float* at = att + 4 * l;
  const float* bt = att + 128 + 4 * l;
  float at0 = at[0], at1 = at[1], at2 = at[2], at3 = at[3];
  float bt0 = bt[0], bt1 = bt[1], bt2 = bt[2], bt3 = bt[3];
  uint2 ur0 = *(const uint2*)(XR0 + (size_t)d * 128 + 4 * l);
  uint2 ur1 = *(const uint2*)(XR1 + (size_t)d * 128 + 4 * l);
  float xa0 = lo16(ur0.x), xa1 = hi16(ur0.x), xa2 = lo16(ur0.y), xa3 = hi16(ur0.y);
  float xb0 = lo16(ur1.x), xb1 = hi16(ur1.x), xb2 = lo16(ur1.y), xb3 = hi16(ur1.y);
  // per-head 0.6 * sum(att * xr), reduced once per wave
  float qa = at0 * xa0; qa = fmaf(at1, xa1, qa);
  qa = fmaf(at2, xa2, qa); qa = fmaf(at3, xa3, qa);
  qa = 0.6f * rsum16(qa);
  float qb = bt0 * xb0; qb = fmaf(bt1, xb1, qb);
  qb = fmaf(bt2, xb2, qb); qb = fmaf(bt3, xb3, qb);
  qb = 0.6f * rsum16(qb);
  EdgeAcc A = {0.f, 0.f, 0.f, 0.f, 0.f};
  EdgeAcc B = {0.f, 0.f, 0.f, 0.f, 0.f};
  {  // relation 0: quad-unrolled (4 row-gathers in flight per wave)
    int j = beg0 + half;
    for (; j + 6 < end0; j += 8) {
      int s0 = csd0[j].x, s1 = csd0[j + 2].x;
      int s2 = csd0[j + 4].x, s3 = csd0[j + 6].x;
      uint2 u0 = *(const uint2*)(XL0 + (size_t)s0 * 128 + 4 * l);
      uint2 u1 = *(const uint2*)(XL0 + (size_t)s1 * 128 + 4 * l);
      uint2 u2 = *(const uint2*)(XL0 + (size_t)s2 * 128 + 4 * l);
      uint2 u3 = *(const uint2*)(XL0 + (size_t)s3 * 128 + 4 * l);
      edge_step(u0, xa0, xa1, xa2, xa3, at0, at1, at2, at3, qa, A);
      edge_step(u1, xa0, xa1, xa2, xa3, at0, at1, at2, at3, qa, A);
      edge_step(u2, xa0, xa1, xa2, xa3, at0, at1, at2, at3, qa, A);
      edge_step(u3, xa0, xa1, xa2, xa3, at0, at1, at2, at3, qa, A);
    }
    for (; j < end0; j += 2) {
      int s = csd0[j].x;
      uint2 u = *(const uint2*)(XL0 + (size_t)s * 128 + 4 * l);
      edge_step(u, xa0, xa1, xa2, xa3, at0, at1, at2, at3, qa, A);
    }
  }
  {  // relation 1: quad-unrolled
    int j = beg1 + half;
    for (; j + 6 < end1; j += 8) {
      int s0 = csd1[j].x, s1 = csd1[j + 2].x;
      int s2 = csd1[j + 4].x, s3 = csd1[j + 6].x;
      uint2 u0 = *(const uint2*)(XL1 + (size_t)s0 * 128 + 4 * l);
      uint2 u1 = *(const uint2*)(XL1 + (size_t)s1 * 128 + 4 * l);
      uint2 u2 = *(const uint2*)(XL1 + (size_t)s2 * 128 + 4 * l);
      uint2 u3 = *(const uint2*)(XL1 + (size_t)s3 * 128 + 4 * l);
      edge_step(u0, xb0, xb1, xb2, xb3, bt0, bt1, bt2, bt3, qb, B);
      edge_step(u1, xb0, xb1, xb2, xb3, bt0, bt1, bt2, bt3, qb, B);
      edge_step(u2, xb0, xb1, xb2, xb3, bt0, bt1, bt2, bt3, qb, B);
      edge_step(u3, xb0, xb1, xb2, xb3, bt0, bt1, bt2, bt3, qb, B);
    }
    for (; j < end1; j += 2) {
      int s = csd1[j].x;
      uint2 u = *(const uint2*)(XL1 + (size_t)s * 128 + 4 * l);
      edge_step(u, xb0, xb1, xb2, xb3, bt0, bt1, bt2, bt3, qb, B);
    }
  }
  // combine edge-parity halves for both relations
#define C32(v) v += __shfl_xor(v, 32);
  C32(A.den) C32(A.a0) C32(A.a1) C32(A.a2) C32(A.a3)
  C32(B.den) C32(B.a0) C32(B.a1) C32(B.a2) C32(B.a3)
#undef C32
  float invA = 1.f / (A.den + 1e-16f);
  float invB = 1.f / (B.den + 1e-16f);
  A.a0 *= invA; A.a1 *= invA; A.a2 *= invA; A.a3 *= invA;
  B.a0 *= invB; B.a1 *= invB; B.a2 *= invB; B.a3 *= invB;
  // head mean per relation
  float t0 = 0.5f * (A.a0 + __shfl_xor(A.a0, 16));
  float t1 = 0.5f * (A.a1 + __shfl_xor(A.a1, 16));
  float t2 = 0.5f * (A.a2 + __shfl_xor(A.a2, 16));
  float t3 = 0.5f * (A.a3 + __shfl_xor(A.a3, 16));
  float u0 = 0.5f * (B.a0 + __shfl_xor(B.a0, 16));
  float u1 = 0.5f * (B.a1 + __shfl_xor(B.a1, 16));
  float u2 = 0.5f * (B.a2 + __shfl_xor(B.a2, 16));
  float u3 = 0.5f * (B.a3 + __shfl_xor(B.a3, 16));
  if (lane >= 16) return;
  int c0 = 4 * lane;
  t0 += bias[c0]; t1 += bias[c0 + 1]; t2 += bias[c0 + 2]; t3 += bias[c0 + 3];
  u0 += bias[64 + c0]; u1 += bias[64 + c0 + 1];
  u2 += bias[64 + c0 + 2]; u3 += bias[64 + c0 + 3];
  float v0 = 0.5f * (t0 + u0);
  float v1 = 0.5f * (t1 + u1);
  float v2 = 0.5f * (t2 + u2);
  float v3 = 0.5f * (t3 + u3);
  *(float4*)(outf + (size_t)d * 64 + c0) = make_float4(v0, v1, v2, v3);
}

extern "C" void kernel_launch(void* const* d_in, const int* in_sizes, int n_in,
                              void* d_out, int out_size, void* d_ws, size_t ws_size,
                              hipStream_t stream) {
  const float* x       = (const float*)d_in[0];
  const int*   e_adj   = (const int*)d_in[1];
  const int*   e_ray   = (const int*)d_in[2];
  const float* l1_Wl   = (const float*)d_in[3];
  const float* l1_bl   = (const float*)d_in[4];
  const float* l1_Wr   = (const float*)d_in[5];
  const float* l1_br   = (const float*)d_in[6];
  const float* l1_att  = (const float*)d_in[7];
  const float* l1_bias = (const float*)d_in[8];
  const float* l2_Wl   = (const float*)d_in[9];
  const float* l2_bl   = (const float*)d_in[10];
  const float* l2_Wr   = (const float*)d_in[11];
  const float* l2_br   = (const float*)d_in[12];
  const float* l2_att  = (const float*)d_in[13];
  const float* l2_bias = (const float*)d_in[14];
  float* out = (float*)d_out;

  char* w = (char*)d_ws;
  size_t off = 0;
  auto alloc = [&](size_t bytes) -> char* {
    char* p = w + off;
    off += (bytes + 255) & ~(size_t)255;
    return p;
  };
  bf16* XL0  = (bf16*)alloc((size_t)N_PAD * 128 * 2);   // layer-2 transforms only
  bf16* XR0  = (bf16*)alloc((size_t)N_PAD * 128 * 2);
  bf16* XL1  = (bf16*)alloc((size_t)N_PAD * 128 * 2);
  bf16* XR1  = (bf16*)alloc((size_t)N_PAD * 128 * 2);
  bf16* HB   = (bf16*)alloc((size_t)N_PAD * 64 * 2);
  short* WT  = (short*)alloc(2 * 16384 * 2);
  int* RP0   = (int*)alloc((size_t)(N_NODES + 1) * 4);
  int* RP1   = (int*)alloc((size_t)(N_NODES + 1) * 4);
  int* FI0   = (int*)alloc((size_t)N_NODES * 4);
  int* FI1   = (int*)alloc((size_t)N_NODES * 4);
  int2* CSD0 = (int2*)alloc((size_t)E_EDGES * 8);
  int2* CSD1 = (int2*)alloc((size_t)E_EDGES * 8);
  int* BSUM  = (int*)alloc(2 * NBLK * 4);
  float* L1C = (float*)alloc(20 * 4);
  float* SCG = (float*)alloc(2 * 768 * 4);

  // Layer-1 scratch OVERLAYS the XL0 region: EX4 25.6 MB. Lifetime ends at
  // l1aggfin_k, before mfma_t_k writes XL0 (stream-ordered).
  float4* EX4 = (float4*)XL0;
  // Rank arrays OVERLAY the XL1 region (6.4 MB of 25.6): lifetime ends at
  // scat_rank_k, before mfma_t_k writes XL1 (stream-ordered).
  int* RK0    = (int*)XL1;
  int* RK1    = (int*)((char*)XL1 + 3200000);

  const int* src_adj = e_adj;
  const int* dst_adj = e_adj + E_EDGES;
  const int* src_ray = e_ray;
  const int* dst_ray = e_ray + E_EDGES;

  const int WNB = (N_NODES * 64) / 256;    // 25000 (one wave per node)
  const int MB  = N_PAD / 128;             // 782

  // ---- CSR build: rank pass (fi doubles as degree) + scan + blind scatter ----
  size_t fispan = (size_t)((char*)FI1 - (char*)FI0) + (size_t)N_NODES * 4;
  hipMemsetAsync(FI0, 0, fispan, stream);
  rank_k<<<dim3(RBLK, 2), 256, 0, stream>>>(dst_adj, dst_ray, FI0, FI1, RK0, RK1);
  scan_blk_k<<<dim3(NBLK, 2), 1024, 0, stream>>>(FI0, FI1, RP0, RP1, BSUM);
  scan_add_k<<<dim3(NBLK, 2), 1024, 0, stream>>>(BSUM, RP0, RP1, FI0, FI1);
  scat_rank_k<<<dim3(EBLK, 2), 256, 0, stream>>>(src_adj, dst_adj, src_ray, dst_ray,
                                                 RK0, RK1, RP0, RP1, CSD0, CSD1);
  wprep_k<<<129, 256, 0, stream>>>(l2_Wl, l2_Wr, WT,
                                   l1_Wl, l1_bl, l1_Wr, l1_br, l1_att, L1C, SCG);

  // ---- layer 1: edge-parallel scoring + fused agg/finish ----
  l1score_k<<<dim3(EBLK, 2), 256, 0, stream>>>(CSD0, CSD1, x, SCG, L1C, EX4);
  l1aggfin_k<<<(N_NODES + 63) / 64, 256, 0, stream>>>(RP0, RP1, EX4,
                                                      l1_Wl, l1_bl, l1_bias,
                                                      (uint2*)HB);

  // ---- layer 2 (K=64): one MFMA dispatch, ONE fused aggregation dispatch ----
  mfma_t_k<<<dim3(MB, 1, 2), 256, 0, stream>>>(HB, WT, l2_bl, l2_br,
                                               XL0, XR0, XL1, XR1);
  aggf_k<<<WNB, 256, 0, stream>>>(RP0, CSD0, RP1, CSD1, XL0, XR0, XL1, XR1,
                                  l2_att, l2_bias, out);
}

// Round 14
// 394.135 us; speedup vs baseline: 1.0605x; 1.0605x over previous
//
#include <hip/hip_runtime.h>
#include <hip/hip_bf16.h>

typedef __hip_bfloat16 bf16;
typedef unsigned int uint;
typedef unsigned short ushort;
typedef __attribute__((ext_vector_type(8))) short short8;  // 8 x bf16 (4 VGPRs)
typedef __attribute__((ext_vector_type(4))) float floatx4;

#define N_NODES 100000
#define N_PAD   100096   // multiple of 128 for the MFMA row tiling
#define E_EDGES 800000
#define NBLK    98       // ceil(N_NODES / 1024)
#define EBLK    3125     // E_EDGES / 256 (exact)
#define RBLK    782      // rank_k blocks: 782*256 = 200192 threads, 4 edges each

static __device__ __forceinline__ uint packbf(float a, float b) {
  bf16 x = __float2bfloat16(a), y = __float2bfloat16(b);
  ushort ux = *reinterpret_cast<ushort*>(&x);
  ushort uy = *reinterpret_cast<ushort*>(&y);
  return (uint)ux | ((uint)uy << 16);
}
static __device__ __forceinline__ float lo16(uint u) { return __uint_as_float(u << 16); }
static __device__ __forceinline__ float hi16(uint u) { return __uint_as_float(u & 0xffff0000u); }

// sum over each DPP row (16 lanes) via cyclic rotations 8,4,2,1 — every lane
// ends with the full 16-lane sum. Pure VALU (v_add dpp), no LDS pipe.
static __device__ __forceinline__ float rsum16(float p) {
  p += __int_as_float(__builtin_amdgcn_update_dpp(
      0, __float_as_int(p), 0x128, 0xF, 0xF, false));  // row_ror:8
  p += __int_as_float(__builtin_amdgcn_update_dpp(
      0, __float_as_int(p), 0x124, 0xF, 0xF, false));  // row_ror:4
  p += __int_as_float(__builtin_amdgcn_update_dpp(
      0, __float_as_int(p), 0x122, 0xF, 0xF, false));  // row_ror:2
  p += __int_as_float(__builtin_amdgcn_update_dpp(
      0, __float_as_int(p), 0x121, 0xF, 0xF, false));  // row_ror:1
  return p;
}

// ---------------- CSR build: rank-based (r10-proven) -------------------------
// Rank pass: returning atomics only — all 4 pipeline freely. fi ends as degree.
__global__ __launch_bounds__(256) void rank_k(
    const int* __restrict__ dst0, const int* __restrict__ dst1,
    int* fi0, int* fi1, int* __restrict__ rk0, int* __restrict__ rk1) {
  int base = blockIdx.x * 256 + threadIdx.x;   // 0 .. 200191
  int rel = blockIdx.y;
  const int* dst = rel ? dst1 : dst0;
  int* fi = rel ? fi1 : fi0;
  int* rk = rel ? rk1 : rk0;
#pragma unroll
  for (int k = 0; k < 4; ++k) {
    int i = base + k * (RBLK * 256);
    if (i < E_EDGES) {
      int d = dst[i];
      rk[i] = atomicAdd(&fi[d], 1);
    }
  }
}

// Scatter with NO atomics: pos = rp[dst] + rank. Store is fire-and-forget.
__global__ __launch_bounds__(256) void scat_rank_k(
    const int* __restrict__ src0, const int* __restrict__ dst0,
    const int* __restrict__ src1, const int* __restrict__ dst1,
    const int* __restrict__ rk0, const int* __restrict__ rk1,
    const int* __restrict__ rp0, const int* __restrict__ rp1,
    int2* __restrict__ csd0, int2* __restrict__ csd1) {
  int i = blockIdx.x * 256 + threadIdx.x;
  int rel = blockIdx.y;
  const int* src = rel ? src1 : src0;
  const int* dst = rel ? dst1 : dst0;
  const int* rk = rel ? rk1 : rk0;
  const int* rp = rel ? rp1 : rp0;
  int2* csd = rel ? csd1 : csd0;
  int d = dst[i];
  int s = src[i];
  int pos = rp[d] + rk[i];
  csd[pos] = make_int2(s, d);
}

// shfl-based scan: 2 barriers instead of 20.
__global__ void scan_blk_k(const int* __restrict__ deg0, const int* __restrict__ deg1,
                           int* rp0, int* rp1, int* bsum) {
  __shared__ int ws[16];
  int r = blockIdx.y;
  const int* deg = r ? deg1 : deg0;
  int* rp = r ? rp1 : rp0;
  int i = blockIdx.x * 1024 + threadIdx.x;
  int v = (i < N_NODES) ? deg[i] : 0;
  int lane = threadIdx.x & 63, wid = threadIdx.x >> 6;
  int s = v;
#pragma unroll
  for (int off = 1; off < 64; off <<= 1) {
    int t = __shfl_up(s, off);
    if (lane >= off) s += t;
  }
  if (lane == 63) ws[wid] = s;
  __syncthreads();
  if (wid == 0) {
    int wv = (lane < 16) ? ws[lane] : 0;
#pragma unroll
    for (int off = 1; off < 16; off <<= 1) {
      int t = __shfl_up(wv, off);
      if (lane >= off) wv += t;
    }
    if (lane < 16) ws[lane] = wv;
  }
  __syncthreads();
  int base = wid ? ws[wid - 1] : 0;
  int incl = base + s;
  if (i < N_NODES) rp[i] = incl - v;              // exclusive prefix
  if (threadIdx.x == 1023) bsum[r * NBLK + blockIdx.x] = incl;  // block total
}

__global__ void scan_top_k(int* bsum, int* rp0, int* rp1) {
  __shared__ int s[128];
  int r = blockIdx.x;
  int v = (threadIdx.x < NBLK) ? bsum[r * NBLK + threadIdx.x] : 0;
  s[threadIdx.x] = v;
  __syncthreads();
  for (int off = 1; off < 128; off <<= 1) {
    int t = (threadIdx.x >= off) ? s[threadIdx.x - off] : 0;
    __syncthreads();
    s[threadIdx.x] += t;
    __syncthreads();
  }
  if (threadIdx.x < NBLK) bsum[r * NBLK + threadIdx.x] = s[threadIdx.x] - v;
  if (threadIdx.x == 127) (r ? rp1 : rp0)[N_NODES] = s[127];
}

__global__ void scan_add_k(const int* __restrict__ bsum,
                           int* rp0, int* rp1, int* fi0, int* fi1) {
  int r = blockIdx.y;
  int i = blockIdx.x * 1024 + threadIdx.x;
  if (i >= N_NODES) return;
  int* rp = r ? rp1 : rp0;
  int* fi = r ? fi1 : fi0;
  int val = rp[i] + bsum[r * NBLK + blockIdx.x];
  rp[i] = val;
  fi[i] = val;
}

// ---------------- layer-2 weight prep + layer-1 tables ----------------------
__global__ void wprep_k(const float* __restrict__ Wl, const float* __restrict__ Wr,
                        short* __restrict__ WT,
                        const float* __restrict__ l1Wl, const float* __restrict__ l1bl,
                        const float* __restrict__ l1Wr, const float* __restrict__ l1br,
                        const float* __restrict__ l1att, float* __restrict__ L1C,
                        float* __restrict__ SCG) {
  if (blockIdx.x == 128) {
    __shared__ float lps[20][8];
    int t = threadIdx.x;
    {  // SCG fill: 2 rel x 128 channels, 6 values each
      int rel = t >> 7, c = t & 127;
      int ch = c >> 2, o = c & 3;
      float* g = SCG + rel * 768 + ch * 24;
      g[0 + o]  = l1bl[rel * 128 + c] + l1br[rel * 128 + c];
      g[4 + o]  = l1Wr[rel * 256 + c];
      g[8 + o]  = l1Wr[rel * 256 + 128 + c];
      g[12 + o] = l1Wl[rel * 256 + c];
      g[16 + o] = l1Wl[rel * 256 + 128 + c];
      g[20 + o] = l1att[rel * 128 + c];
    }
    // L1C: 20 values x 64 terms, parallel over 160 threads (8 terms each)
    if (t < 160) {
      int v5 = t >> 3, kk = t & 7;
      int rel = v5 / 10, rem = v5 % 10, h = rem / 5, vv = rem % 5;
      const float* a = l1att + rel * 128 + h * 64;
      float sum = 0.f;
      for (int c = kk * 8; c < kk * 8 + 8; ++c) {
        int cc = h * 64 + c;
        float val;
        if (vv == 0)      val = l1bl[rel * 128 + cc] + l1br[rel * 128 + cc];
        else if (vv == 1) val = l1Wr[rel * 256 + cc];
        else if (vv == 2) val = l1Wr[rel * 256 + 128 + cc];
        else if (vv == 3) val = l1Wl[rel * 256 + cc];
        else              val = l1Wl[rel * 256 + 128 + cc];
        sum += a[c] * val;
      }
      lps[v5][kk] = sum;
    }
    __syncthreads();
    if (t < 20) {
      float s = 0.f;
#pragma unroll
      for (int j = 0; j < 8; ++j) s += lps[t][j];
      L1C[t] = s;
    }
    return;
  }
  int id2 = blockIdx.x * 256 + threadIdx.x;
  int rel = id2 >> 14;
  int id = id2 & 16383;
  int c = id >> 6, k = id & 63;
  const float* W = (c < 128) ? (Wl + rel * 8192) : (Wr + rel * 8192);
  int cc = c & 127;
  bf16 b = __float2bfloat16(W[k * 128 + cc]);
  WT[rel * 16384 + c * 64 + k] = *reinterpret_cast<short*>(&b);
}

// ---------------- layer-1 scoring: EDGE-parallel, one lane = one edge --------
__global__ __launch_bounds__(256) void l1score_k(
    const int2* __restrict__ csd0, const int2* __restrict__ csd1,
    const float* __restrict__ x,
    const float* __restrict__ scg, const float* __restrict__ l1c,
    float4* __restrict__ EX4) {
  int rel = blockIdx.y;
  const int2* csd = rel ? csd1 : csd0;
  const float* sC = scg + rel * 768;
  const float* C = l1c + rel * 10;
  float q00 = C[0], qv00 = C[1], qv10 = C[2], qw00 = C[3], qw10 = C[4];
  float q01 = C[5], qv01 = C[6], qv11 = C[7], qw01 = C[8], qw11 = C[9];
  int i = blockIdx.x * 256 + threadIdx.x;  // grid is exact: 3125*256 == E_EDGES
  int2 sd = csd[i];
  int s = sd.x, d = sd.y;
  float2 xs = *(const float2*)(x + 2 * s);
  float2 xd = *(const float2*)(x + 2 * d);
  float t0a = 0.f, t0b = 0.f, t1a = 0.f, t1b = 0.f;
#pragma unroll
  for (int ch = 0; ch < 32; ++ch) {
    const float4* cp = (const float4*)(sC + ch * 24);  // uniform address
    float4 bb = cp[0], v0 = cp[1], v1 = cp[2], w0 = cp[3], w1 = cp[4], aa = cp[5];
    float e0 = bb.x + xd.x * v0.x + xd.y * v1.x + xs.x * w0.x + xs.y * w1.x;
    float e1 = bb.y + xd.x * v0.y + xd.y * v1.y + xs.x * w0.y + xs.y * w1.y;
    float e2 = bb.z + xd.x * v0.z + xd.y * v1.z + xs.x * w0.z + xs.y * w1.z;
    float e3 = bb.w + xd.x * v0.w + xd.y * v1.w + xs.x * w0.w + xs.y * w1.w;
    if (ch < 16) {
      t0a = fmaf(aa.x, fabsf(e0), t0a); t0b = fmaf(aa.y, fabsf(e1), t0b);
      t0a = fmaf(aa.z, fabsf(e2), t0a); t0b = fmaf(aa.w, fabsf(e3), t0b);
    } else {
      t1a = fmaf(aa.x, fabsf(e0), t1a); t1b = fmaf(aa.y, fabsf(e1), t1b);
      t1a = fmaf(aa.z, fabsf(e2), t1a); t1b = fmaf(aa.w, fabsf(e3), t1b);
    }
  }
  float T0 = t0a + t0b, T1 = t1a + t1b;
  float lin0 = q00 + xd.x * qv00 + xd.y * qv10 + xs.x * qw00 + xs.y * qw10;
  float lin1 = q01 + xd.x * qv01 + xd.y * qv11 + xs.x * qw01 + xs.y * qw11;
  float p0 = fmaf(0.4f, T0, 0.6f * lin0);
  float p1 = fmaf(0.4f, T1, 0.6f * lin1);
  EX4[(size_t)rel * E_EDGES + i] = make_float4(__expf(p0), __expf(p1), xs.x, xs.y);
}

// ------- layer-1 agg + finish FUSED: LDS handoff, no NA global round-trip ----
__global__ __launch_bounds__(256) void l1aggfin_k(
    const int* __restrict__ rp0, const int* __restrict__ rp1,
    const float4* __restrict__ EX4,
    const float* __restrict__ Wl, const float* __restrict__ bl,
    const float* __restrict__ bias, uint2* __restrict__ HB2) {
  __shared__ __align__(16) float sNA[64][12];
  int t = threadIdx.x;
  int g = blockIdx.x * 64 + (t >> 2);   // dst for phase 1
  int k = t & 3;
  float p0 = 0.f, p1 = 0.f, p2 = 0.f, p3 = 0.f, p4 = 0.f, p5 = 0.f;
  float p6 = 0.f, p7 = 0.f, p8 = 0.f, p9 = 0.f, p10 = 0.f, p11 = 0.f;
  if (g < N_NODES) {
    {
      int beg = rp0[g], end = rp0[g + 1];
      for (int j = beg + k; j < end; j += 4) {
        float4 e = EX4[j];
        p0 += e.x; p1 = fmaf(e.x, e.z, p1); p2 = fmaf(e.x, e.w, p2);
        p3 += e.y; p4 = fmaf(e.y, e.z, p4); p5 = fmaf(e.y, e.w, p5);
      }
    }
    {
      const float4* E1 = EX4 + E_EDGES;
      int beg = rp1[g], end = rp1[g + 1];
      for (int j = beg + k; j < end; j += 4) {
        float4 e = E1[j];
        p6 += e.x; p7 = fmaf(e.x, e.z, p7); p8 = fmaf(e.x, e.w, p8);
        p9 += e.y; p10 = fmaf(e.y, e.z, p10); p11 = fmaf(e.y, e.w, p11);
      }
    }
  }
#define RED4(v) v += __shfl_xor(v, 1); v += __shfl_xor(v, 2);
  RED4(p0) RED4(p1) RED4(p2) RED4(p3) RED4(p4) RED4(p5)
  RED4(p6) RED4(p7) RED4(p8) RED4(p9) RED4(p10) RED4(p11)
#undef RED4
  {
    int dl = t >> 2;
    if (k == 0)      *(float4*)(&sNA[dl][0]) = make_float4(p0, p1, p2, p3);
    else if (k == 1) *(float4*)(&sNA[dl][4]) = make_float4(p4, p5, p6, p7);
    else if (k == 2) *(float4*)(&sNA[dl][8]) = make_float4(p8, p9, p10, p11);
  }
  __syncthreads();
#pragma unroll
  for (int rep = 0; rep < 4; ++rep) {
    int idx = rep * 256 + t;            // 0..1023
    int dl = idx >> 4, l = idx & 15;
    int d = blockIdx.x * 64 + dl;
    if (d >= N_NODES) continue;
    int c0 = 4 * l;
    const float* na = sNA[dl];
    float out0 = 0.f, out1 = 0.f, out2 = 0.f, out3 = 0.f;
#pragma unroll
    for (int r = 0; r < 2; ++r) {
      float a0c = 0.f, a1c = 0.f, a2c = 0.f, a3c = 0.f;
#pragma unroll
      for (int h = 0; h < 2; ++h) {
        float den = na[r * 6 + h * 3 + 0];
        float A0  = na[r * 6 + h * 3 + 1];
        float A1  = na[r * 6 + h * 3 + 2];
        float inv = 1.f / (den + 1e-16f);
        float a0 = A0 * inv, a1 = A1 * inv, S = den * inv;  // S: 1 normally, 0 empty
        float4 W0 = *(const float4*)(Wl + r * 256 + h * 64 + c0);
        float4 W1 = *(const float4*)(Wl + r * 256 + 128 + h * 64 + c0);
        float4 B  = *(const float4*)(bl + r * 128 + h * 64 + c0);
        a0c += a0 * W0.x + a1 * W1.x + S * B.x;
        a1c += a0 * W0.y + a1 * W1.y + S * B.y;
        a2c += a0 * W0.z + a1 * W1.z + S * B.z;
        a3c += a0 * W0.w + a1 * W1.w + S * B.w;
      }
      float4 bi = *(const float4*)(bias + r * 64 + c0);
      out0 += 0.5f * a0c + bi.x;
      out1 += 0.5f * a1c + bi.y;
      out2 += 0.5f * a2c + bi.z;
      out3 += 0.5f * a3c + bi.w;
    }
    out0 = fmaxf(0.5f * out0, 0.f); out1 = fmaxf(0.5f * out1, 0.f);
    out2 = fmaxf(0.5f * out2, 0.f); out3 = fmaxf(0.5f * out3, 0.f);
    HB2[(size_t)d * 16 + l] = make_uint2(packbf(out0, out1), packbf(out2, out3));
  }
}

// ---------------- layer-2 transform: swapped operands -> packed row stores ---
__global__ __launch_bounds__(256) void mfma_t_k(const bf16* __restrict__ HB,
                                                const short* __restrict__ WTb,
                                                const float* __restrict__ blb,
                                                const float* __restrict__ brb,
                                                bf16* __restrict__ XL0,
                                                bf16* __restrict__ XR0,
                                                bf16* __restrict__ XL1,
                                                bf16* __restrict__ XR1) {
  __shared__ short sW[256 * 72];
  int rel = blockIdx.z;
  const short* WT = WTb + rel * 16384;
  const float* bl = blb + rel * 128;
  const float* br = brb + rel * 128;
  bf16* XLp = rel ? XL1 : XL0;
  bf16* XRp = rel ? XR1 : XR0;
  int t = threadIdx.x;
#pragma unroll
  for (int i = 0; i < 8; ++i) {
    int chunk = t + i * 256;
    int c = chunk >> 3, off = (chunk & 7) * 8;
    *(short8*)(&sW[c * 72 + off]) = *(const short8*)(WT + chunk * 8);
  }
  __syncthreads();
  int wave = t >> 6, lane = t & 63;
  int q = lane >> 4, m = lane & 15;
  int rowbase = blockIdx.x * 128 + wave * 32;
  short8 afr[2][2];
#pragma unroll
  for (int rt = 0; rt < 2; ++rt)
#pragma unroll
    for (int kh = 0; kh < 2; ++kh) {
      size_t row = (size_t)(rowbase + rt * 16 + m);
      afr[rt][kh] = *(const short8*)((const short*)HB + row * 64 + kh * 32 + q * 8);
    }
  for (int ct = 0; ct < 16; ++ct) {
    int col = ct * 16 + m;
    short8 b0 = *(const short8*)(&sW[col * 72 + q * 8]);
    short8 b1 = *(const short8*)(&sW[col * 72 + 32 + q * 8]);
    int c0 = ct * 16 + q * 4;
    int c128 = c0 & 127;
    const float* bp = (ct < 8) ? bl : br;
    bf16* X = (ct < 8) ? XLp : XRp;
    float4 bv = *(const float4*)(bp + c128);
#pragma unroll
    for (int rt = 0; rt < 2; ++rt) {
      floatx4 acc = {0.f, 0.f, 0.f, 0.f};
      acc = __builtin_amdgcn_mfma_f32_16x16x32_bf16(b0, afr[rt][0], acc, 0, 0, 0);
      acc = __builtin_amdgcn_mfma_f32_16x16x32_bf16(b1, afr[rt][1], acc, 0, 0, 0);
      int node = rowbase + rt * 16 + m;
      if (node < N_NODES) {
        uint u0 = packbf(acc[0] + bv.x, acc[1] + bv.y);
        uint u1 = packbf(acc[2] + bv.z, acc[3] + bv.w);
        *(uint2*)((ushort*)X + (size_t)node * 128 + c128) = make_uint2(u0, u1);
      }
    }
  }
}

// ------- layer-2 agg: fused relations, 32 lanes/edge, quad-unrolled MLP=4 ----
struct EdgeAcc { float a0, a1, a2, a3, den; };

// abs-split score: p = 0.6*(sx + sxr) + 0.4*sum att|e|; the 0.6*sxr head-total
// (q06) is precomputed per wave. fabsf folds into the VOP3 input modifier.
static __device__ __forceinline__ void edge_step(
    uint2 u, float xr0, float xr1, float xr2, float xr3,
    float at0, float at1, float at2, float at3, float q06, EdgeAcc& A) {
  float x0 = lo16(u.x), x1 = hi16(u.x), x2 = lo16(u.y), x3 = hi16(u.y);
  float e0 = x0 + xr0, e1 = x1 + xr1, e2 = x2 + xr2, e3 = x3 + xr3;
  float sa = at0 * fabsf(e0);
  sa = fmaf(at1, fabsf(e1), sa);
  sa = fmaf(at2, fabsf(e2), sa);
  sa = fmaf(at3, fabsf(e3), sa);
  float sx = at0 * x0;
  sx = fmaf(at1, x1, sx);
  sx = fmaf(at2, x2, sx);
  sx = fmaf(at3, x3, sx);
  float p = fmaf(0.6f, sx, 0.4f * sa);
  p = rsum16(p);                // 16-lane head-group total, pure VALU DPP
  float ex = __expf(p + q06);
  A.den += ex;
  A.a0 = fmaf(ex, x0, A.a0);
  A.a1 = fmaf(ex, x1, A.a1);
  A.a2 = fmaf(ex, x2, A.a2);
  A.a3 = fmaf(ex, x3, A.a3);
}

__global__ __launch_bounds__(256) void aggf_k(
    const int* __restrict__ rp0, const int2* __restrict__ csd0,
    const int* __restrict__ rp1, const int2* __restrict__ csd1,
    const bf16* __restrict__ XL0, const bf16* __restrict__ XR0,
    const bf16* __restrict__ XL1, const bf16* __restrict__ XR1,
    const float* __restrict__ att,    // [256]: rel0 at +0, rel1 at +128
    const float* __restrict__ bias,   // [128]: rel0 at +0, rel1 at +64
    float* __restrict__ outf) {
  int d = (blockIdx.x * 256 + threadIdx.x) >> 6;
  int lane = threadIdx.x & 63;
  if (d >= N_NODES) return;
  int half = lane >> 5;
  int l = lane & 31;
  int beg0 = rp0[d], end0 = rp0[d + 1];
  int beg1 = rp1[d], end1 = rp1[d + 1];
  const float* at = att + 4 * l;
  const float* bt = att + 128 + 4 * l;
  float at0 = at[0], at1 = at[1], at2 = at[2], at3 = at[3];
  float bt0 = bt[0], bt1 = bt[1], bt2 = bt[2], bt3 = bt[3];
  uint2 ur0 = *(const uint2*)(XR0 + (size_t)d * 128 + 4 * l);
  uint2 ur1 = *(const uint2*)(XR1 + (size_t)d * 128 + 4 * l);
  float xa0 = lo16(ur0.x), xa1 = hi16(ur0.x), xa2 = lo16(ur0.y), xa3 = hi16(ur0.y);
  float xb0 = lo16(ur1.x), xb1 = hi16(ur1.x), xb2 = lo16(ur1.y), xb3 = hi16(ur1.y);
  // per-head 0.6 * sum(att * xr), reduced once per wave
  float qa = at0 * xa0; qa = fmaf(at1, xa1, qa);
  qa = fmaf(at2, xa2, qa); qa = fmaf(at3, xa3, qa);
  qa = 0.6f * rsum16(qa);
  float qb = bt0 * xb0; qb = fmaf(bt1, xb1, qb);
  qb = fmaf(bt2, xb2, qb); qb = fmaf(bt3, xb3, qb);
  qb = 0.6f * rsum16(qb);
  EdgeAcc A = {0.f, 0.f, 0.f, 0.f, 0.f};
  EdgeAcc B = {0.f, 0.f, 0.f, 0.f, 0.f};
  {  // relation 0: quad-unrolled (4 row-gathers in flight per wave)
    int j = beg0 + half;
    for (; j + 6 < end0; j += 8) {
      int s0 = csd0[j].x, s1 = csd0[j + 2].x;
      int s2 = csd0[j + 4].x, s3 = csd0[j + 6].x;
      uint2 u0 = *(const uint2*)(XL0 + (size_t)s0 * 128 + 4 * l);
      uint2 u1 = *(const uint2*)(XL0 + (size_t)s1 * 128 + 4 * l);
      uint2 u2 = *(const uint2*)(XL0 + (size_t)s2 * 128 + 4 * l);
      uint2 u3 = *(const uint2*)(XL0 + (size_t)s3 * 128 + 4 * l);
      edge_step(u0, xa0, xa1, xa2, xa3, at0, at1, at2, at3, qa, A);
      edge_step(u1, xa0, xa1, xa2, xa3, at0, at1, at2, at3, qa, A);
      edge_step(u2, xa0, xa1, xa2, xa3, at0, at1, at2, at3, qa, A);
      edge_step(u3, xa0, xa1, xa2, xa3, at0, at1, at2, at3, qa, A);
    }
    for (; j < end0; j += 2) {
      int s = csd0[j].x;
      uint2 u = *(const uint2*)(XL0 + (size_t)s * 128 + 4 * l);
      edge_step(u, xa0, xa1, xa2, xa3, at0, at1, at2, at3, qa, A);
    }
  }
  {  // relation 1: quad-unrolled
    int j = beg1 + half;
    for (; j + 6 < end1; j += 8) {
      int s0 = csd1[j].x, s1 = csd1[j + 2].x;
      int s2 = csd1[j + 4].x, s3 = csd1[j + 6].x;
      uint2 u0 = *(const uint2*)(XL1 + (size_t)s0 * 128 + 4 * l);
      uint2 u1 = *(const uint2*)(XL1 + (size_t)s1 * 128 + 4 * l);
      uint2 u2 = *(const uint2*)(XL1 + (size_t)s2 * 128 + 4 * l);
      uint2 u3 = *(const uint2*)(XL1 + (size_t)s3 * 128 + 4 * l);
      edge_step(u0, xb0, xb1, xb2, xb3, bt0, bt1, bt2, bt3, qb, B);
      edge_step(u1, xb0, xb1, xb2, xb3, bt0, bt1, bt2, bt3, qb, B);
      edge_step(u2, xb0, xb1, xb2, xb3, bt0, bt1, bt2, bt3, qb, B);
      edge_step(u3, xb0, xb1, xb2, xb3, bt0, bt1, bt2, bt3, qb, B);
    }
    for (; j < end1; j += 2) {
      int s = csd1[j].x;
      uint2 u = *(const uint2*)(XL1 + (size_t)s * 128 + 4 * l);
      edge_step(u, xb0, xb1, xb2, xb3, bt0, bt1, bt2, bt3, qb, B);
    }
  }
  // combine edge-parity halves for both relations
#define C32(v) v += __shfl_xor(v, 32);
  C32(A.den) C32(A.a0) C32(A.a1) C32(A.a2) C32(A.a3)
  C32(B.den) C32(B.a0) C32(B.a1) C32(B.a2) C32(B.a3)
#undef C32
  float invA = 1.f / (A.den + 1e-16f);
  float invB = 1.f / (B.den + 1e-16f);
  A.a0 *= invA; A.a1 *= invA; A.a2 *= invA; A.a3 *= invA;
  B.a0 *= invB; B.a1 *= invB; B.a2 *= invB; B.a3 *= invB;
  // head mean per relation
  float t0 = 0.5f * (A.a0 + __shfl_xor(A.a0, 16));
  float t1 = 0.5f * (A.a1 + __shfl_xor(A.a1, 16));
  float t2 = 0.5f * (A.a2 + __shfl_xor(A.a2, 16));
  float t3 = 0.5f * (A.a3 + __shfl_xor(A.a3, 16));
  float u0 = 0.5f * (B.a0 + __shfl_xor(B.a0, 16));
  float u1 = 0.5f * (B.a1 + __shfl_xor(B.a1, 16));
  float u2 = 0.5f * (B.a2 + __shfl_xor(B.a2, 16));
  float u3 = 0.5f * (B.a3 + __shfl_xor(B.a3, 16));
  if (lane >= 16) return;
  int c0 = 4 * lane;
  t0 += bias[c0]; t1 += bias[c0 + 1]; t2 += bias[c0 + 2]; t3 += bias[c0 + 3];
  u0 += bias[64 + c0]; u1 += bias[64 + c0 + 1];
  u2 += bias[64 + c0 + 2]; u3 += bias[64 + c0 + 3];
  float v0 = 0.5f * (t0 + u0);
  float v1 = 0.5f * (t1 + u1);
  float v2 = 0.5f * (t2 + u2);
  float v3 = 0.5f * (t3 + u3);
  *(float4*)(outf + (size_t)d * 64 + c0) = make_float4(v0, v1, v2, v3);
}

extern "C" void kernel_launch(void* const* d_in, const int* in_sizes, int n_in,
                              void* d_out, int out_size, void* d_ws, size_t ws_size,
                              hipStream_t stream) {
  const float* x       = (const float*)d_in[0];
  const int*   e_adj   = (const int*)d_in[1];
  const int*   e_ray   = (const int*)d_in[2];
  const float* l1_Wl   = (const float*)d_in[3];
  const float* l1_bl   = (const float*)d_in[4];
  const float* l1_Wr   = (const float*)d_in[5];
  const float* l1_br   = (const float*)d_in[6];
  const float* l1_att  = (const float*)d_in[7];
  const float* l1_bias = (const float*)d_in[8];
  const float* l2_Wl   = (const float*)d_in[9];
  const float* l2_bl   = (const float*)d_in[10];
  const float* l2_Wr   = (const float*)d_in[11];
  const float* l2_br   = (const float*)d_in[12];
  const float* l2_att  = (const float*)d_in[13];
  const float* l2_bias = (const float*)d_in[14];
  float* out = (float*)d_out;

  char* w = (char*)d_ws;
  size_t off = 0;
  auto alloc = [&](size_t bytes) -> char* {
    char* p = w + off;
    off += (bytes + 255) & ~(size_t)255;
    return p;
  };
  bf16* XL0  = (bf16*)alloc((size_t)N_PAD * 128 * 2);   // layer-2 transforms only
  bf16* XR0  = (bf16*)alloc((size_t)N_PAD * 128 * 2);
  bf16* XL1  = (bf16*)alloc((size_t)N_PAD * 128 * 2);
  bf16* XR1  = (bf16*)alloc((size_t)N_PAD * 128 * 2);
  bf16* HB   = (bf16*)alloc((size_t)N_PAD * 64 * 2);
  short* WT  = (short*)alloc(2 * 16384 * 2);
  int* RP0   = (int*)alloc((size_t)(N_NODES + 1) * 4);
  int* RP1   = (int*)alloc((size_t)(N_NODES + 1) * 4);
  int* FI0   = (int*)alloc((size_t)N_NODES * 4);
  int* FI1   = (int*)alloc((size_t)N_NODES * 4);
  int2* CSD0 = (int2*)alloc((size_t)E_EDGES * 8);
  int2* CSD1 = (int2*)alloc((size_t)E_EDGES * 8);
  int* BSUM  = (int*)alloc(2 * NBLK * 4);
  float* L1C = (float*)alloc(20 * 4);
  float* SCG = (float*)alloc(2 * 768 * 4);

  // Layer-1 scratch OVERLAYS the XL0 region: EX4 25.6 MB. Lifetime ends at
  // l1aggfin_k, before mfma_t_k writes XL0 (stream-ordered).
  float4* EX4 = (float4*)XL0;
  // Rank arrays OVERLAY the XL1 region (6.4 MB of 25.6): lifetime ends at
  // scat_rank_k, before mfma_t_k writes XL1 (stream-ordered).
  int* RK0    = (int*)XL1;
  int* RK1    = (int*)((char*)XL1 + 3200000);

  const int* src_adj = e_adj;
  const int* dst_adj = e_adj + E_EDGES;
  const int* src_ray = e_ray;
  const int* dst_ray = e_ray + E_EDGES;

  const int WNB = (N_NODES * 64) / 256;    // 25000 (one wave per node)
  const int MB  = N_PAD / 128;             // 782

  // ---- CSR build: rank pass (fi doubles as degree) + scan + blind scatter ----
  size_t fispan = (size_t)((char*)FI1 - (char*)FI0) + (size_t)N_NODES * 4;
  hipMemsetAsync(FI0, 0, fispan, stream);
  rank_k<<<dim3(RBLK, 2), 256, 0, stream>>>(dst_adj, dst_ray, FI0, FI1, RK0, RK1);
  scan_blk_k<<<dim3(NBLK, 2), 1024, 0, stream>>>(FI0, FI1, RP0, RP1, BSUM);
  scan_top_k<<<2, 128, 0, stream>>>(BSUM, RP0, RP1);
  scan_add_k<<<dim3(NBLK, 2), 1024, 0, stream>>>(BSUM, RP0, RP1, FI0, FI1);
  scat_rank_k<<<dim3(EBLK, 2), 256, 0, stream>>>(src_adj, dst_adj, src_ray, dst_ray,
                                                 RK0, RK1, RP0, RP1, CSD0, CSD1);
  wprep_k<<<129, 256, 0, stream>>>(l2_Wl, l2_Wr, WT,
                                   l1_Wl, l1_bl, l1_Wr, l1_br, l1_att, L1C, SCG);

  // ---- layer 1: edge-parallel scoring + fused agg/finish ----
  l1score_k<<<dim3(EBLK, 2), 256, 0, stream>>>(CSD0, CSD1, x, SCG, L1C, EX4);
  l1aggfin_k<<<(N_NODES + 63) / 64, 256, 0, stream>>>(RP0, RP1, EX4,
                                                      l1_Wl, l1_bl, l1_bias,
                                                      (uint2*)HB);

  // ---- layer 2 (K=64): one MFMA dispatch, ONE fused aggregation dispatch ----
  mfma_t_k<<<dim3(MB, 1, 2), 256, 0, stream>>>(HB, WT, l2_bl, l2_br,
                                               XL0, XR0, XL1, XR1);
  aggf_k<<<WNB, 256, 0, stream>>>(RP0, CSD0, RP1, CSD1, XL0, XR0, XL1, XR1,
                                  l2_att, l2_bias, out);
}